// Round 4
// baseline (304.605 us; speedup 1.0000x reference)
//
#include <hip/hip_runtime.h>
#include <stdint.h>

// DCNv2 fused forward (B=8, C=256, H=W=64, OC=256, 3x3, pad=1, stride=1, DG=1)
// bf16 hi/lo 3-product GEMM (proven R3 numerics), now with a single-barrier
// software-pipelined K-loop:
//   - A (weights) staged via global_load_lds (async DMA) into double-buffered LDS
//   - B (cols) corner loads prefetched to regs at loop top, bilinear+pack+ds_write
//     into the other buffer AFTER the MFMA section
//   - one __syncthreads per K-step; its implicit vmcnt(0) drain sits after a full
//     MFMA section of in-flight time (AITER-style)
// Tile 128 oc x 64 pos, grid 1024 (b = blk&7 for XCD/L2 xtf locality).
// LDS chunk-major [hl][chunk4][row][16B]: conflict-free b128 frag reads, and the
// DMA dest is wave-uniform-base + lane*16 as required.

typedef __attribute__((ext_vector_type(8))) short bf16x8;
typedef __attribute__((ext_vector_type(4))) float floatx4;
typedef __attribute__((ext_vector_type(4))) unsigned int uintx4;

#define MFMA16(A, B, C) __builtin_amdgcn_mfma_f32_16x16x32_bf16(A, B, C, 0, 0, 0)

__device__ __forceinline__ float bf2f(unsigned int u) {
    union { unsigned int i; float f; } v; v.i = u << 16; return v.f;
}
__device__ __forceinline__ unsigned int f2bf_rne(float f) {
    union { float f; unsigned int i; } v; v.f = f;
    unsigned int u = v.i;
    u += 0x7fffu + ((u >> 16) & 1u);
    return u >> 16;
}
__device__ __forceinline__ void split_bf(float v, unsigned int& h, unsigned int& l) {
    h = f2bf_rne(v);
    l = f2bf_rne(v - bf2f(h));
}

// async 16B/lane global->LDS DMA (dest must be wave-uniform base + lane*16)
__device__ __forceinline__ void gld16(const unsigned short* g, unsigned short* l) {
    __builtin_amdgcn_global_load_lds(
        (__attribute__((address_space(1))) void*)const_cast<unsigned short*>(g),
        (__attribute__((address_space(3))) void*)l, 16, 0, 0);
}

// pack hi16(v0) | hi16(v1)<<16  (exact bf16-truncation of the pair)
__device__ __forceinline__ unsigned int pack_hibits(float v0, float v1) {
    union { float f; unsigned int u; } a, b; a.f = v0; b.f = v1;
    return __builtin_amdgcn_perm(b.u, a.u, 0x07060302u);
}

// per-thread bilinear coords for (tap, ho, wo)
__device__ __forceinline__ void mk_coords(int tap, int ho, int wo,
    float offy, float offx, float m,
    int& yx00, int& yx01, int& yx10, int& yx11,
    float& w00, float& w01, float& w10, float& w11) {
    float py = (float)(tap / 3) + (float)(ho - 1) + offy;
    float px = (float)(tap % 3) + (float)(wo - 1) + offx;
    float y0f = floorf(py), x0f = floorf(px);
    float wy1 = py - y0f, wx1 = px - x0f;
    float wy0 = 1.f - wy1, wx0 = 1.f - wx1;
    int y0 = (int)y0f, x0 = (int)x0f, y1 = y0 + 1, x1 = x0 + 1;
    bool vy0 = (y0 >= 0) && (y0 < 64), vy1 = (y1 >= 0) && (y1 < 64);
    bool vx0 = (x0 >= 0) && (x0 < 64), vx1 = (x1 >= 0) && (x1 < 64);
    int cy0 = min(max(y0, 0), 63), cy1 = min(max(y1, 0), 63);
    int cx0 = min(max(x0, 0), 63), cx1 = min(max(x1, 0), 63);
    yx00 = cy0 * 64 + cx0; yx01 = cy0 * 64 + cx1;
    yx10 = cy1 * 64 + cx0; yx11 = cy1 * 64 + cx1;
    w00 = wy0 * wx0 * m * ((vy0 && vx0) ? 1.f : 0.f);
    w01 = wy0 * wx1 * m * ((vy0 && vx1) ? 1.f : 0.f);
    w10 = wy1 * wx0 * m * ((vy1 && vx0) ? 1.f : 0.f);
    w11 = wy1 * wx1 * m * ((vy1 && vx1) ? 1.f : 0.f);
}

// exact-hi + trunc-lo split of 8 vals -> packed bf16 pairs
__device__ __forceinline__ void split_pack8(const float* vals, uintx4& pkH, uintx4& pkL) {
#pragma unroll
    for (int p = 0; p < 4; p++) {
        float v0 = vals[2 * p], v1 = vals[2 * p + 1];
        pkH[p] = pack_hibits(v0, v1);
        union { unsigned int u; float f; } h0, h1;
        union { float f; unsigned int u; } a, b; a.f = v0; b.f = v1;
        h0.u = a.u & 0xffff0000u; h1.u = b.u & 0xffff0000u;
        float r0 = v0 - h0.f, r1 = v1 - h1.f;   // exact residuals
        pkL[p] = pack_hibits(r0, r1);
    }
}

// ---- prep: x (8,256,64,64) f32 -> xtf (8,4096,256) f32, tiled transpose ----
__global__ __launch_bounds__(256) void k_prep_xt(const float* __restrict__ x,
                                                 float* __restrict__ xtf) {
    __shared__ float T[64][65];
    const int blk = blockIdx.x;       // 8 * 4 * 64 = 2048
    const int b = blk >> 8;
    const int ct = (blk >> 6) & 3;    // channel tile (64)
    const int tt = blk & 63;          // pixel tile (64)
    const int t = threadIdx.x;
    const int jj = t & 63, i4 = t >> 6;
    const float* xb = x + ((size_t)b << 20);
#pragma unroll 4
    for (int ii = 0; ii < 16; ii++) {
        int i = ii * 4 + i4;
        T[i][jj] = xb[((size_t)(ct * 64 + i) << 12) + tt * 64 + jj];
    }
    __syncthreads();
    float* ob = xtf + ((size_t)b << 20);
#pragma unroll 4
    for (int ii = 0; ii < 16; ii++) {
        int jo = ii * 4 + i4;
        ob[((size_t)(tt * 64 + jo) << 8) + ct * 64 + jj] = T[jj][jo];
    }
}

// ---- prep: weight -> bw2[step72][hl2][chunk4][oc256][8k] bf16 ----
__global__ __launch_bounds__(256) void k_prep_w2(const float* __restrict__ w,
                                                 unsigned short* __restrict__ bw2) {
    int tid = blockIdx.x * 256 + threadIdx.x;   // 72*16384 = 1179648
    int j = tid & 7;
    int oc = (tid >> 3) & 255;
    int c = (tid >> 11) & 3;
    int hl = (tid >> 13) & 1;
    int step = tid >> 14;
    int ktap = step >> 3;
    int ch = ((step & 7) << 5) + (c << 3) + j;
    float v = w[oc * 2304 + ch * 9 + ktap];
    unsigned int h, l;
    split_bf(v, h, l);
    bw2[tid] = (unsigned short)(hl ? l : h);
}

// ---- main: pipelined, single barrier per K-step ----
__global__ __launch_bounds__(256, 2) void k_dcn_pipe(
    const float* __restrict__ offset,  // (8,18,64,64)
    const float* __restrict__ mask,    // (8,9,64,64)
    const float* __restrict__ bias,    // (256,)
    const float* __restrict__ xtf,     // (8,4096,256) f32
    const unsigned short* __restrict__ bw2,  // (72,2,4,256,8) bf16
    float* __restrict__ out)           // (8,256,64,64)
{
    // per buffer: A = [hl][chunk4][row128][8] = 8192 ush; B = [hl][chunk4][pos64][8] = 4096 ush
    __shared__ __align__(16) unsigned short As[2 * 8192];   // 32 KB
    __shared__ __align__(16) unsigned short Bs[2 * 4096];   // 16 KB

    const int t = threadIdx.x;
    const int tile = blockIdx.x;        // 1024
    const int b = tile & 7;             // XCD locality
    const int ho = (tile >> 3) & 63;
    const int ocH = tile >> 9;          // 0/1

    const int lane = t & 63, wid = t >> 6, quad = lane >> 4, l15 = lane & 15;
    const int gpos = t >> 2, gseg = t & 3;
    const int wo = gpos;
    const int spos = (ho << 6) + wo;

    const float* xb = xtf + ((size_t)b << 20);

    floatx4 acc[2][4];
#pragma unroll
    for (int i = 0; i < 2; i++)
#pragma unroll
        for (int j = 0; j < 4; j++) acc[i][j] = (floatx4){0.f, 0.f, 0.f, 0.f};

    // tap-0 coords + tap-1 raw prefetch (per-thread, no LDS)
    int yx00, yx01, yx10, yx11; float w00, w01, w10, w11;
    {
        float oy = offset[((size_t)(b * 18 + 0) << 12) + spos];
        float ox = offset[((size_t)(b * 18 + 1) << 12) + spos];
        float mm = mask[((size_t)(b * 9 + 0) << 12) + spos];
        mk_coords(0, ho, wo, oy, ox, mm, yx00, yx01, yx10, yx11, w00, w01, w10, w11);
    }
    float noy = offset[((size_t)(b * 18 + 2) << 12) + spos];
    float nox = offset[((size_t)(b * 18 + 3) << 12) + spos];
    float nmm = mask[((size_t)(b * 9 + 1) << 12) + spos];

    // prologue: stage step 0 into buffer 0
#pragma unroll
    for (int r = 0; r < 4; r++) {
        int rr = r * 256 + t;
        int hl = rr >> 9, c = (rr >> 7) & 3, row = rr & 127;
        gld16(bw2 + hl * 8192 + c * 2048 + (ocH * 128 + row) * 8,
              &As[hl * 4096 + c * 1024 + row * 8]);
    }
    {
        const int cb = gseg << 3;   // cs = 0
        const float* p00 = xb + ((size_t)yx00 << 8) + cb;
        const float* p01 = xb + ((size_t)yx01 << 8) + cb;
        const float* p10 = xb + ((size_t)yx10 << 8) + cb;
        const float* p11 = xb + ((size_t)yx11 << 8) + cb;
        floatx4 a0 = *(const floatx4*)p00, a1 = *(const floatx4*)(p00 + 4);
        floatx4 b0 = *(const floatx4*)p01, b1 = *(const floatx4*)(p01 + 4);
        floatx4 g0 = *(const floatx4*)p10, g1 = *(const floatx4*)(p10 + 4);
        floatx4 d0 = *(const floatx4*)p11, d1 = *(const floatx4*)(p11 + 4);
        float vals[8];
#pragma unroll
        for (int q = 0; q < 4; q++) {
            vals[q]     = w00 * a0[q] + w01 * b0[q] + w10 * g0[q] + w11 * d0[q];
            vals[4 + q] = w00 * a1[q] + w01 * b1[q] + w10 * g1[q] + w11 * d1[q];
        }
        uintx4 pkH, pkL;
        split_pack8(vals, pkH, pkL);
        *(uintx4*)&Bs[gseg * 512 + gpos * 8] = pkH;
        *(uintx4*)&Bs[2048 + gseg * 512 + gpos * 8] = pkL;
    }
    __syncthreads();   // drains DMA (vmcnt) + ds_writes

    for (int k = 0; k < 72; k++) {
        const int p = k & 1;
        const unsigned short* AsP = As + p * 8192;
        const unsigned short* BsP = Bs + p * 4096;

        floatx4 c00a, c00b, c01a, c01b, c10a, c10b, c11a, c11b;
        const bool pf = (k < 71);
        if (pf) {
            const int kn = k + 1;
            if ((kn & 7) == 0) {
                const int tn = kn >> 3;   // 1..8
                mk_coords(tn, ho, wo, noy, nox, nmm,
                          yx00, yx01, yx10, yx11, w00, w01, w10, w11);
                if (tn < 8) {
                    noy = offset[((size_t)(b * 18 + 2 * tn + 2) << 12) + spos];
                    nox = offset[((size_t)(b * 18 + 2 * tn + 3) << 12) + spos];
                    nmm = mask[((size_t)(b * 9 + tn + 1) << 12) + spos];
                }
            }
            // async DMA A(k+1) into the other buffer — in flight through the MFMA section
#pragma unroll
            for (int r = 0; r < 4; r++) {
                int rr = r * 256 + t;
                int hl = rr >> 9, c = (rr >> 7) & 3, row = rr & 127;
                gld16(bw2 + (size_t)kn * 16384 + hl * 8192 + c * 2048 + (ocH * 128 + row) * 8,
                      &As[(1 - p) * 8192 + hl * 4096 + c * 1024 + row * 8]);
            }
            // corner loads for k+1 -> regs
            const int cb = ((kn & 7) << 5) + (gseg << 3);
            const float* p00 = xb + ((size_t)yx00 << 8) + cb;
            const float* p01 = xb + ((size_t)yx01 << 8) + cb;
            const float* p10 = xb + ((size_t)yx10 << 8) + cb;
            const float* p11 = xb + ((size_t)yx11 << 8) + cb;
            c00a = *(const floatx4*)p00; c00b = *(const floatx4*)(p00 + 4);
            c01a = *(const floatx4*)p01; c01b = *(const floatx4*)(p01 + 4);
            c10a = *(const floatx4*)p10; c10b = *(const floatx4*)(p10 + 4);
            c11a = *(const floatx4*)p11; c11b = *(const floatx4*)(p11 + 4);
        }

        // ---- fragments + 3-product MFMA on buffer p ----
        bf16x8 aH[2], aL[2], bH[4], bL[4];
#pragma unroll
        for (int i = 0; i < 2; i++) {
            const int rowA = (wid << 5) + (i << 4) + l15;
            aH[i] = *(const bf16x8*)&AsP[quad * 1024 + rowA * 8];
            aL[i] = *(const bf16x8*)&AsP[4096 + quad * 1024 + rowA * 8];
        }
#pragma unroll
        for (int j = 0; j < 4; j++) {
            const int rowB = (j << 4) + l15;
            bH[j] = *(const bf16x8*)&BsP[quad * 512 + rowB * 8];
            bL[j] = *(const bf16x8*)&BsP[2048 + quad * 512 + rowB * 8];
        }
#pragma unroll
        for (int i = 0; i < 2; i++)
#pragma unroll
            for (int j = 0; j < 4; j++) {
                acc[i][j] = MFMA16(aH[i], bH[j], acc[i][j]);
                acc[i][j] = MFMA16(aL[i], bH[j], acc[i][j]);
                acc[i][j] = MFMA16(aH[i], bL[j], acc[i][j]);
            }

        if (pf) {
            // bilinear + split/pack + write into the other B buffer (no barrier needed:
            // buffer (1-p) is not being read this step)
            float vals[8];
#pragma unroll
            for (int q = 0; q < 4; q++) {
                vals[q]     = w00 * c00a[q] + w01 * c01a[q] + w10 * c10a[q] + w11 * c11a[q];
                vals[4 + q] = w00 * c00b[q] + w01 * c01b[q] + w10 * c10b[q] + w11 * c11b[q];
            }
            uintx4 pkH, pkL;
            split_pack8(vals, pkH, pkL);
            *(uintx4*)&Bs[(1 - p) * 4096 + gseg * 512 + gpos * 8] = pkH;
            *(uintx4*)&Bs[(1 - p) * 4096 + 2048 + gseg * 512 + gpos * 8] = pkL;
        }
        __syncthreads();   // single per-step barrier: drains A-DMA + B ds_writes
    }

    // ---- epilogue: C/D col=lane&15 -> pos, row=quad*4+r -> oc ----
    float* outb = out + ((size_t)b << 20);
    const int posbase = ho << 6;
#pragma unroll
    for (int i = 0; i < 2; i++) {
        const int ocb = ocH * 128 + (wid << 5) + (i << 4) + (quad << 2);
#pragma unroll
        for (int r = 0; r < 4; r++) {
            const float bv = bias[ocb + r];
#pragma unroll
            for (int j = 0; j < 4; j++) {
                const int pos = posbase + (j << 4) + l15;
                outb[((size_t)(ocb + r) << 12) + pos] = acc[i][j][r] + bv;
            }
        }
    }
}

// ---- fallback (no workspace): R3-proven unpipelined kernel, direct reads ----
__global__ __launch_bounds__(256, 2) void k_dcn_fb(
    const float* __restrict__ x, const float* __restrict__ offset,
    const float* __restrict__ mask, const float* __restrict__ weight,
    const float* __restrict__ bias, float* __restrict__ out)
{
    __shared__ __align__(16) unsigned short AsH[256 * 40];
    __shared__ __align__(16) unsigned short AsL[256 * 40];
    __shared__ __align__(16) unsigned short BsH[64 * 40];
    __shared__ __align__(16) unsigned short BsL[64 * 40];
    __shared__ int cY[64][4];
    __shared__ float cW[64][4];

    const int t = threadIdx.x;
    const int tile = blockIdx.x;   // 512
    const int b = tile >> 6;
    const int ho = tile & 63;
    const int lane = t & 63, wid = t >> 6, quad = lane >> 4, l15 = lane & 15;
    const int gpos = t >> 2, gseg = t & 3;

    floatx4 acc[4][4];
#pragma unroll
    for (int i = 0; i < 4; i++)
#pragma unroll
        for (int j = 0; j < 4; j++) acc[i][j] = (floatx4){0.f, 0.f, 0.f, 0.f};

    for (int ktap = 0; ktap < 9; ++ktap) {
        __syncthreads();
        if (t < 64) {
            int wo = t;
            int spos = (ho << 6) + wo;
            float offy = offset[(((size_t)(b * 18 + 2 * ktap)) << 12) + spos];
            float offx = offset[(((size_t)(b * 18 + 2 * ktap + 1)) << 12) + spos];
            float m = mask[(((size_t)(b * 9 + ktap)) << 12) + spos];
            int c0, c1, c2, c3; float u0, u1, u2, u3;
            mk_coords(ktap, ho, wo, offy, offx, m, c0, c1, c2, c3, u0, u1, u2, u3);
            cY[t][0] = c0; cY[t][1] = c1; cY[t][2] = c2; cY[t][3] = c3;
            cW[t][0] = u0; cW[t][1] = u1; cW[t][2] = u2; cW[t][3] = u3;
        }
        __syncthreads();
        const int yx00 = cY[gpos][0], yx01 = cY[gpos][1];
        const int yx10 = cY[gpos][2], yx11 = cY[gpos][3];
        const float w00 = cW[gpos][0], w01 = cW[gpos][1];
        const float w10 = cW[gpos][2], w11 = cW[gpos][3];

        for (int cs = 0; cs < 8; ++cs) {
            const int c0 = cs << 5;
            {
                const float* wp = weight + (size_t)t * 2304 + (size_t)c0 * 9 + ktap;
#pragma unroll
                for (int kj = 0; kj < 32; kj += 2) {
                    unsigned int h0, l0u, h1, l1u;
                    split_bf(wp[kj * 9], h0, l0u);
                    split_bf(wp[kj * 9 + 9], h1, l1u);
                    *(unsigned int*)&AsH[t * 40 + kj] = h0 | (h1 << 16);
                    *(unsigned int*)&AsL[t * 40 + kj] = l0u | (l1u << 16);
                }
            }
            {
                const int cb = c0 + (gseg << 3);
                const float* xg = x + ((size_t)b << 20);
                float vals[8];
#pragma unroll
                for (int j = 0; j < 8; j++) {
                    const float* xc = xg + ((size_t)(cb + j) << 12);
                    vals[j] = w00 * xc[yx00] + w01 * xc[yx01] +
                              w10 * xc[yx10] + w11 * xc[yx11];
                }
                uintx4 pkH, pkL;
                split_pack8(vals, pkH, pkL);
                *(uintx4*)&BsH[gpos * 40 + (gseg << 3)] = pkH;
                *(uintx4*)&BsL[gpos * 40 + (gseg << 3)] = pkL;
            }
            __syncthreads();
            bf16x8 aH[4], aL[4], bH[4], bL[4];
#pragma unroll
            for (int i = 0; i < 4; i++) {
                const int rowA = (wid << 6) + (i << 4) + l15;
                aH[i] = *(const bf16x8*)&AsH[rowA * 40 + (quad << 3)];
                aL[i] = *(const bf16x8*)&AsL[rowA * 40 + (quad << 3)];
            }
#pragma unroll
            for (int j = 0; j < 4; j++) {
                const int rowB = (j << 4) + l15;
                bH[j] = *(const bf16x8*)&BsH[rowB * 40 + (quad << 3)];
                bL[j] = *(const bf16x8*)&BsL[rowB * 40 + (quad << 3)];
            }
#pragma unroll
            for (int i = 0; i < 4; i++)
#pragma unroll
                for (int j = 0; j < 4; j++) {
                    acc[i][j] = MFMA16(aH[i], bH[j], acc[i][j]);
                    acc[i][j] = MFMA16(aL[i], bH[j], acc[i][j]);
                    acc[i][j] = MFMA16(aH[i], bL[j], acc[i][j]);
                }
            __syncthreads();
        }
    }
    float* outb = out + ((size_t)b << 20);
    const int posbase = ho << 6;
#pragma unroll
    for (int i = 0; i < 4; i++) {
        const int ocb = (wid << 6) + (i << 4) + (quad << 2);
#pragma unroll
        for (int r = 0; r < 4; r++) {
            const float bv = bias[ocb + r];
#pragma unroll
            for (int j = 0; j < 4; j++) {
                const int pos = posbase + (j << 4) + l15;
                outb[((size_t)(ocb + r) << 12) + pos] = acc[i][j][r] + bv;
            }
        }
    }
}

extern "C" void kernel_launch(void* const* d_in, const int* in_sizes, int n_in,
                              void* d_out, int out_size, void* d_ws, size_t ws_size,
                              hipStream_t stream) {
    const float* x      = (const float*)d_in[0];
    const float* offset = (const float*)d_in[1];
    const float* mask   = (const float*)d_in[2];
    const float* weight = (const float*)d_in[3];
    const float* bias   = (const float*)d_in[4];
    float* out = (float*)d_out;

    const size_t xtf_bytes = (size_t)8 * 4096 * 256 * 4;       // 32 MB
    const size_t bw2_elems = (size_t)72 * 16384;               // 1179648 ush
    const size_t need = xtf_bytes + bw2_elems * 2;             // ~34.25 MB

    if (ws_size >= need) {
        float* xtf = (float*)d_ws;
        unsigned short* bw2 = (unsigned short*)((char*)d_ws + xtf_bytes);
        k_prep_xt<<<2048, 256, 0, stream>>>(x, xtf);
        k_prep_w2<<<(int)(bw2_elems / 256), 256, 0, stream>>>(weight, bw2);
        k_dcn_pipe<<<1024, 256, 0, stream>>>(offset, mask, bias, xtf, bw2, out);
    } else {
        k_dcn_fb<<<512, 256, 0, stream>>>(x, offset, mask, weight, bias, out);
    }
}

// Round 5
// 226.624 us; speedup vs baseline: 1.3441x; 1.3441x over previous
//
#include <hip/hip_runtime.h>
#include <stdint.h>

// DCNv2 fused forward (B=8, C=256, H=W=64, OC=256, 3x3, pad=1, stride=1, DG=1)
// bf16 hi/lo 3-product GEMM, R5 structure:
//  - Tile 256 oc x 64 pos (grid 512 = 2 blocks/CU; cols generated ONCE per pos tile)
//  - A (weights): NO LDS. Each wave loads its 8 A-fragments (hi/lo x 4 rows) as
//    global dwordx4 from pre-tiled bw2 (L2-hot, 2.4 MB), register double-buffered
//    one K-step ahead -> fine-grained vmcnt waits, no barrier drain.
//  - B (cols): LDS double-buffered; corner loads for k+1 issued at step top (in
//    flight across MFMA), bilinear+pack+ds_write after MFMA; ONE barrier per step
//    (drains only lgkmcnt/ds_writes).
//  - B LDS swizzle: chunk stride 528 ush (1056 B) -> conflict-free b128 writes+reads.

typedef __attribute__((ext_vector_type(8))) short bf16x8;
typedef __attribute__((ext_vector_type(4))) float floatx4;
typedef __attribute__((ext_vector_type(4))) unsigned int uintx4;

#define MFMA16(A, B, C) __builtin_amdgcn_mfma_f32_16x16x32_bf16(A, B, C, 0, 0, 0)

__device__ __forceinline__ float bf2f(unsigned int u) {
    union { unsigned int i; float f; } v; v.i = u << 16; return v.f;
}
__device__ __forceinline__ unsigned int f2bf_rne(float f) {
    union { float f; unsigned int i; } v; v.f = f;
    unsigned int u = v.i;
    u += 0x7fffu + ((u >> 16) & 1u);
    return u >> 16;
}
__device__ __forceinline__ void split_bf(float v, unsigned int& h, unsigned int& l) {
    h = f2bf_rne(v);
    l = f2bf_rne(v - bf2f(h));
}
// pack hi16(v0) | hi16(v1)<<16
__device__ __forceinline__ unsigned int pack_hibits(float v0, float v1) {
    union { float f; unsigned int u; } a, b; a.f = v0; b.f = v1;
    return __builtin_amdgcn_perm(b.u, a.u, 0x07060302u);
}
// exact-hi + trunc-lo split of 8 vals -> packed bf16 pairs (R3/R4-proven numerics)
__device__ __forceinline__ void split_pack8(const float* vals, uintx4& pkH, uintx4& pkL) {
#pragma unroll
    for (int p = 0; p < 4; p++) {
        float v0 = vals[2 * p], v1 = vals[2 * p + 1];
        pkH[p] = pack_hibits(v0, v1);
        union { unsigned int u; float f; } h0, h1;
        union { float f; unsigned int u; } a, b; a.f = v0; b.f = v1;
        h0.u = a.u & 0xffff0000u; h1.u = b.u & 0xffff0000u;
        pkL[p] = pack_hibits(v0 - h0.f, v1 - h1.f);
    }
}

__device__ __forceinline__ void mk_coords(int tap, int ho, int wo,
    float offy, float offx, float m,
    int& yx00, int& yx01, int& yx10, int& yx11,
    float& w00, float& w01, float& w10, float& w11) {
    float py = (float)(tap / 3) + (float)(ho - 1) + offy;
    float px = (float)(tap % 3) + (float)(wo - 1) + offx;
    float y0f = floorf(py), x0f = floorf(px);
    float wy1 = py - y0f, wx1 = px - x0f;
    float wy0 = 1.f - wy1, wx0 = 1.f - wx1;
    int y0 = (int)y0f, x0 = (int)x0f, y1 = y0 + 1, x1 = x0 + 1;
    bool vy0 = (y0 >= 0) && (y0 < 64), vy1 = (y1 >= 0) && (y1 < 64);
    bool vx0 = (x0 >= 0) && (x0 < 64), vx1 = (x1 >= 0) && (x1 < 64);
    int cy0 = min(max(y0, 0), 63), cy1 = min(max(y1, 0), 63);
    int cx0 = min(max(x0, 0), 63), cx1 = min(max(x1, 0), 63);
    yx00 = cy0 * 64 + cx0; yx01 = cy0 * 64 + cx1;
    yx10 = cy1 * 64 + cx0; yx11 = cy1 * 64 + cx1;
    w00 = wy0 * wx0 * m * ((vy0 && vx0) ? 1.f : 0.f);
    w01 = wy0 * wx1 * m * ((vy0 && vx1) ? 1.f : 0.f);
    w10 = wy1 * wx0 * m * ((vy1 && vx0) ? 1.f : 0.f);
    w11 = wy1 * wx1 * m * ((vy1 && vx1) ? 1.f : 0.f);
}

// ---- prep: x (8,256,64,64) f32 -> xtf (8,4096,256) f32, tiled transpose ----
__global__ __launch_bounds__(256) void k_prep_xt(const float* __restrict__ x,
                                                 float* __restrict__ xtf) {
    __shared__ float T[64][65];
    const int blk = blockIdx.x;       // 2048
    const int b = blk >> 8;
    const int ct = (blk >> 6) & 3;
    const int tt = blk & 63;
    const int t = threadIdx.x;
    const int jj = t & 63, i4 = t >> 6;
    const float* xb = x + ((size_t)b << 20);
#pragma unroll 4
    for (int ii = 0; ii < 16; ii++) {
        int i = ii * 4 + i4;
        T[i][jj] = xb[((size_t)(ct * 64 + i) << 12) + tt * 64 + jj];
    }
    __syncthreads();
    float* ob = xtf + ((size_t)b << 20);
#pragma unroll 4
    for (int ii = 0; ii < 16; ii++) {
        int jo = ii * 4 + i4;
        ob[((size_t)(tt * 64 + jo) << 8) + ct * 64 + jj] = T[jj][jo];
    }
}

// ---- prep: weight -> bw2[step72][hl2][chunk4][oc256][8k] bf16 ----
__global__ __launch_bounds__(256) void k_prep_w2(const float* __restrict__ w,
                                                 unsigned short* __restrict__ bw2) {
    int tid = blockIdx.x * 256 + threadIdx.x;   // 72*16384
    int j = tid & 7;
    int oc = (tid >> 3) & 255;
    int c = (tid >> 11) & 3;
    int hl = (tid >> 13) & 1;
    int step = tid >> 14;
    int ktap = step >> 3;
    int ch = ((step & 7) << 5) + (c << 3) + j;
    float v = w[oc * 2304 + ch * 9 + ktap];
    unsigned int h, l;
    split_bf(v, h, l);
    bw2[tid] = (unsigned short)(hl ? l : h);
}

// ---- main ----
__global__ __launch_bounds__(256, 2) void k_dcn_v5(
    const float* __restrict__ offset,  // (8,18,64,64)
    const float* __restrict__ mask,    // (8,9,64,64)
    const float* __restrict__ bias,    // (256,)
    const float* __restrict__ xtf,     // (8,4096,256) f32
    const unsigned short* __restrict__ bw2,  // (72,2,4,256,8) bf16
    float* __restrict__ out)           // (8,256,64,64)
{
    // B tile: [buf2][hl2][chunk4(stride 528)][pos64][8]; 2*4224 ush = 16.9 KB
    __shared__ __align__(16) unsigned short Bs[2 * 4224];

    const int t = threadIdx.x;
    const int tile = blockIdx.x;   // 512
    const int b = tile & 7;        // XCD/L2 locality
    const int ho = tile >> 3;      // 0..63

    const int lane = t & 63, wid = t >> 6, quad = lane >> 4, l15 = lane & 15;
    const int gpos = t >> 2, gseg = t & 3;
    const int wo = gpos;
    const int spos = (ho << 6) + wo;
    const float* xb = xtf + ((size_t)b << 20);

    // A fragment base (ush): [step][hl][chunk=quad][oc][8], oc = wid*64 + i*16 + l15
    const unsigned short* aBase = bw2 + quad * 2048 + (((wid << 6) + l15) << 3);

    floatx4 acc[4][4];
#pragma unroll
    for (int i = 0; i < 4; i++)
#pragma unroll
        for (int j = 0; j < 4; j++) acc[i][j] = (floatx4){0.f, 0.f, 0.f, 0.f};

    bf16x8 aCur[8], aNxt[8];   // [0..3]=hi rows, [4..7]=lo rows
    floatx4 crn[8];            // 4 corners x 2 floatx4

#define LOAD_A(DST, KK) {                                                   \
    const unsigned short* ap = aBase + (size_t)(KK) * 16384;                \
    _Pragma("unroll")                                                       \
    for (int i = 0; i < 4; i++) {                                           \
        DST[i]     = *(const bf16x8*)(ap + i * 128);                        \
        DST[4 + i] = *(const bf16x8*)(ap + 8192 + i * 128);                 \
    } }

#define LOAD_CRN(KK) {                                                      \
    const int cb = (((KK) & 7) << 5) + (gseg << 3);                         \
    const float* p00 = xb + ((size_t)yx00 << 8) + cb;                       \
    const float* p01 = xb + ((size_t)yx01 << 8) + cb;                       \
    const float* p10 = xb + ((size_t)yx10 << 8) + cb;                       \
    const float* p11 = xb + ((size_t)yx11 << 8) + cb;                       \
    crn[0] = *(const floatx4*)p00; crn[1] = *(const floatx4*)(p00 + 4);     \
    crn[2] = *(const floatx4*)p01; crn[3] = *(const floatx4*)(p01 + 4);     \
    crn[4] = *(const floatx4*)p10; crn[5] = *(const floatx4*)(p10 + 4);     \
    crn[6] = *(const floatx4*)p11; crn[7] = *(const floatx4*)(p11 + 4); }

#define GEN_WRITE(BUF) {                                                    \
    float vals[8];                                                          \
    _Pragma("unroll")                                                       \
    for (int q = 0; q < 4; q++) {                                           \
        vals[q]     = w00 * crn[0][q] + w01 * crn[2][q] +                   \
                      w10 * crn[4][q] + w11 * crn[6][q];                    \
        vals[4 + q] = w00 * crn[1][q] + w01 * crn[3][q] +                   \
                      w10 * crn[5][q] + w11 * crn[7][q];                    \
    }                                                                       \
    uintx4 pkH, pkL;                                                        \
    split_pack8(vals, pkH, pkL);                                            \
    unsigned short* bp = Bs + (BUF) * 4224 + gseg * 528 + (gpos << 3);      \
    *(uintx4*)bp = pkH;                                                     \
    *(uintx4*)(bp + 2112) = pkL; }

#define MFMA_SEC(BUF, AREG) {                                               \
    const unsigned short* Bp = Bs + (BUF) * 4224 + quad * 528;              \
    bf16x8 bH[4], bL[4];                                                    \
    _Pragma("unroll")                                                       \
    for (int j = 0; j < 4; j++) {                                           \
        const int ro = ((j << 4) + l15) << 3;                               \
        bH[j] = *(const bf16x8*)(Bp + ro);                                  \
        bL[j] = *(const bf16x8*)(Bp + 2112 + ro);                           \
    }                                                                       \
    _Pragma("unroll")                                                       \
    for (int i = 0; i < 4; i++)                                             \
    _Pragma("unroll")                                                       \
        for (int j = 0; j < 4; j++) {                                       \
            acc[i][j] = MFMA16(AREG[i], bH[j], acc[i][j]);                  \
            acc[i][j] = MFMA16(AREG[4 + i], bH[j], acc[i][j]);              \
            acc[i][j] = MFMA16(AREG[i], bL[j], acc[i][j]);                  \
        } }

#define STEP(K, AC, AN) {                                                   \
    const bool pf = (K) < 71;                                               \
    if (pf) {                                                               \
        const int kn = (K) + 1;                                             \
        if ((kn & 7) == 0) {                                                \
            const int tn = kn >> 3;                                         \
            mk_coords(tn, ho, wo, noy, nox, nmm,                            \
                      yx00, yx01, yx10, yx11, w00, w01, w10, w11);          \
            if (tn < 8) {                                                   \
                noy = offset[((size_t)(b * 18 + 2 * tn + 2) << 12) + spos]; \
                nox = offset[((size_t)(b * 18 + 2 * tn + 3) << 12) + spos]; \
                nmm = mask[((size_t)(b * 9 + tn + 1) << 12) + spos];        \
            }                                                               \
        }                                                                   \
        LOAD_A(AN, kn);                                                     \
        LOAD_CRN(kn);                                                       \
    }                                                                       \
    MFMA_SEC((K) & 1, AC);                                                  \
    if (pf) GEN_WRITE(((K) + 1) & 1);                                       \
    __syncthreads(); }

    // ---- prologue: tap-0 coords, corners(0), B(0) -> buf0, A(0) -> aCur ----
    int yx00, yx01, yx10, yx11;
    float w00, w01, w10, w11;
    {
        float oy = offset[((size_t)(b * 18 + 0) << 12) + spos];
        float ox = offset[((size_t)(b * 18 + 1) << 12) + spos];
        float mm = mask[((size_t)(b * 9 + 0) << 12) + spos];
        mk_coords(0, ho, wo, oy, ox, mm, yx00, yx01, yx10, yx11, w00, w01, w10, w11);
    }
    float noy = offset[((size_t)(b * 18 + 2) << 12) + spos];
    float nox = offset[((size_t)(b * 18 + 3) << 12) + spos];
    float nmm = mask[((size_t)(b * 9 + 1) << 12) + spos];

    LOAD_A(aCur, 0);
    LOAD_CRN(0);
    GEN_WRITE(0);
    __syncthreads();

    for (int k = 0; k < 72; k += 2) {
        STEP(k, aCur, aNxt);
        STEP(k + 1, aNxt, aCur);
    }

    // ---- epilogue: C/D col=lane&15 -> pos, row=quad*4+r -> oc ----
    float* outb = out + ((size_t)b << 20);
    const int posbase = ho << 6;
#pragma unroll
    for (int i = 0; i < 4; i++) {
        const int ocb = (wid << 6) + (i << 4) + (quad << 2);
#pragma unroll
        for (int r = 0; r < 4; r++) {
            const float bv = bias[ocb + r];
#pragma unroll
            for (int j = 0; j < 4; j++) {
                const int pos = posbase + (j << 4) + l15;
                outb[((size_t)(ocb + r) << 12) + pos] = acc[i][j][r] + bv;
            }
        }
    }
#undef LOAD_A
#undef LOAD_CRN
#undef GEN_WRITE
#undef MFMA_SEC
#undef STEP
}

// ---- fallback (no workspace): R3-proven unpipelined kernel, direct reads ----
__global__ __launch_bounds__(256, 2) void k_dcn_fb(
    const float* __restrict__ x, const float* __restrict__ offset,
    const float* __restrict__ mask, const float* __restrict__ weight,
    const float* __restrict__ bias, float* __restrict__ out)
{
    __shared__ __align__(16) unsigned short AsH[256 * 40];
    __shared__ __align__(16) unsigned short AsL[256 * 40];
    __shared__ __align__(16) unsigned short BsH[64 * 40];
    __shared__ __align__(16) unsigned short BsL[64 * 40];
    __shared__ int cY[64][4];
    __shared__ float cW[64][4];

    const int t = threadIdx.x;
    const int tile = blockIdx.x;   // 512
    const int b = tile >> 6;
    const int ho = tile & 63;
    const int lane = t & 63, wid = t >> 6, quad = lane >> 4, l15 = lane & 15;
    const int gpos = t >> 2, gseg = t & 3;

    floatx4 acc[4][4];
#pragma unroll
    for (int i = 0; i < 4; i++)
#pragma unroll
        for (int j = 0; j < 4; j++) acc[i][j] = (floatx4){0.f, 0.f, 0.f, 0.f};

    for (int ktap = 0; ktap < 9; ++ktap) {
        __syncthreads();
        if (t < 64) {
            int wo = t;
            int spos = (ho << 6) + wo;
            float offy = offset[(((size_t)(b * 18 + 2 * ktap)) << 12) + spos];
            float offx = offset[(((size_t)(b * 18 + 2 * ktap + 1)) << 12) + spos];
            float m = mask[(((size_t)(b * 9 + ktap)) << 12) + spos];
            int c0, c1, c2, c3; float u0, u1, u2, u3;
            mk_coords(ktap, ho, wo, offy, offx, m, c0, c1, c2, c3, u0, u1, u2, u3);
            cY[t][0] = c0; cY[t][1] = c1; cY[t][2] = c2; cY[t][3] = c3;
            cW[t][0] = u0; cW[t][1] = u1; cW[t][2] = u2; cW[t][3] = u3;
        }
        __syncthreads();
        const int yx00 = cY[gpos][0], yx01 = cY[gpos][1];
        const int yx10 = cY[gpos][2], yx11 = cY[gpos][3];
        const float w00 = cW[gpos][0], w01 = cW[gpos][1];
        const float w10 = cW[gpos][2], w11 = cW[gpos][3];

        for (int cs = 0; cs < 8; ++cs) {
            const int c0 = cs << 5;
            {
                const float* wp = weight + (size_t)t * 2304 + (size_t)c0 * 9 + ktap;
#pragma unroll
                for (int kj = 0; kj < 32; kj += 2) {
                    unsigned int h0, l0u, h1, l1u;
                    split_bf(wp[kj * 9], h0, l0u);
                    split_bf(wp[kj * 9 + 9], h1, l1u);
                    *(unsigned int*)&AsH[t * 40 + kj] = h0 | (h1 << 16);
                    *(unsigned int*)&AsL[t * 40 + kj] = l0u | (l1u << 16);
                }
            }
            {
                const int cb = c0 + (gseg << 3);
                const float* xg = x + ((size_t)b << 20);
                float vals[8];
#pragma unroll
                for (int j = 0; j < 8; j++) {
                    const float* xc = xg + ((size_t)(cb + j) << 12);
                    vals[j] = w00 * xc[yx00] + w01 * xc[yx01] +
                              w10 * xc[yx10] + w11 * xc[yx11];
                }
                uintx4 pkH, pkL;
                split_pack8(vals, pkH, pkL);
                *(uintx4*)&BsH[gpos * 40 + (gseg << 3)] = pkH;
                *(uintx4*)&BsL[gpos * 40 + (gseg << 3)] = pkL;
            }
            __syncthreads();
            bf16x8 aH[4], aL[4], bH[4], bL[4];
#pragma unroll
            for (int i = 0; i < 4; i++) {
                const int rowA = (wid << 6) + (i << 4) + l15;
                aH[i] = *(const bf16x8*)&AsH[rowA * 40 + (quad << 3)];
                aL[i] = *(const bf16x8*)&AsL[rowA * 40 + (quad << 3)];
            }
#pragma unroll
            for (int j = 0; j < 4; j++) {
                const int rowB = (j << 4) + l15;
                bH[j] = *(const bf16x8*)&BsH[rowB * 40 + (quad << 3)];
                bL[j] = *(const bf16x8*)&BsL[rowB * 40 + (quad << 3)];
            }
#pragma unroll
            for (int i = 0; i < 4; i++)
#pragma unroll
                for (int j = 0; j < 4; j++) {
                    acc[i][j] = MFMA16(aH[i], bH[j], acc[i][j]);
                    acc[i][j] = MFMA16(aL[i], bH[j], acc[i][j]);
                    acc[i][j] = MFMA16(aH[i], bL[j], acc[i][j]);
                }
            __syncthreads();
        }
    }
    float* outb = out + ((size_t)b << 20);
    const int posbase = ho << 6;
#pragma unroll
    for (int i = 0; i < 4; i++) {
        const int ocb = (wid << 6) + (i << 4) + (quad << 2);
#pragma unroll
        for (int r = 0; r < 4; r++) {
            const float bv = bias[ocb + r];
#pragma unroll
            for (int j = 0; j < 4; j++) {
                const int pos = posbase + (j << 4) + l15;
                outb[((size_t)(ocb + r) << 12) + pos] = acc[i][j][r] + bv;
            }
        }
    }
}

extern "C" void kernel_launch(void* const* d_in, const int* in_sizes, int n_in,
                              void* d_out, int out_size, void* d_ws, size_t ws_size,
                              hipStream_t stream) {
    const float* x      = (const float*)d_in[0];
    const float* offset = (const float*)d_in[1];
    const float* mask   = (const float*)d_in[2];
    const float* weight = (const float*)d_in[3];
    const float* bias   = (const float*)d_in[4];
    float* out = (float*)d_out;

    const size_t xtf_bytes = (size_t)8 * 4096 * 256 * 4;       // 32 MB
    const size_t bw2_elems = (size_t)72 * 16384;               // 1179648 ush
    const size_t need = xtf_bytes + bw2_elems * 2;             // ~34.25 MB

    if (ws_size >= need) {
        float* xtf = (float*)d_ws;
        unsigned short* bw2 = (unsigned short*)((char*)d_ws + xtf_bytes);
        k_prep_xt<<<2048, 256, 0, stream>>>(x, xtf);
        k_prep_w2<<<(int)(bw2_elems / 256), 256, 0, stream>>>(weight, bw2);
        k_dcn_v5<<<512, 256, 0, stream>>>(offset, mask, bias, xtf, bw2, out);
    } else {
        k_dcn_fb<<<512, 256, 0, stream>>>(x, offset, mask, weight, bias, out);
    }
}